// Round 8
// baseline (390.503 us; speedup 1.0000x reference)
//
#include <hip/hip_runtime.h>

#define IN_CAPS 2048
#define K_DIM   16
#define OD      512      // out_caps(32) * out_dim(16)
#define NCH     64       // i-chunks for route partial sums
#define ICH     32       // i's per route chunk
#define ICH_U   4        // i's per k_uhat block
#define NCH_U   (IN_CAPS / ICH_U)   // 512 i-blocks (= s0 partial slices)

__device__ __forceinline__ float dot4(const float4& a, const float4& b) {
    return fmaf(a.x, b.x, fmaf(a.y, b.y, fmaf(a.z, b.z, a.w * b.w)));
}

// K1: u[b,i,od] = sum_k W[i,od,k] * x[b,i,k] (fp32) + per-block s0 partial
// slice (no atomics: R6; no extra pass: R5). Three fixes combined (no prior
// round had all): (1) grid (512, nb/8) -> 4 blocks/CU (R2 lesson),
// (2) x staged in LDS once per block -- R7's "scalar x loads" were really
// per-bb vector-load latency chains pinning VALUBusy at 13%,
// (3) W explicitly double-buffered across the ii loop (R6 idea, now clean).
template<int BTILE>
__global__ __launch_bounds__(256, 4)
void k_uhat(const float* __restrict__ x,     // [..][2048][16] (b0 pre-offset)
            const float* __restrict__ W,     // [2048][512][16]
            float* __restrict__ u,           // [nb][2048][512]
            float* __restrict__ part)        // [nb][NCH_U][512]
{
    const int t   = threadIdx.x;
    const int ib  = blockIdx.x;            // 0..NCH_U-1
    const int i0  = ib * ICH_U;
    const int bl0 = blockIdx.y * BTILE;

    __shared__ float xs[BTILE][ICH_U][K_DIM];
    if (t < BTILE * ICH_U * K_DIM / 4) {   // 16 float4 per b
        const int bb = t >> 4;
        const int r  = t & 15;
        const int ii = r >> 2;
        const int q  = r & 3;
        const float4 v4 = *(const float4*)(
            x + ((size_t)(bl0 + bb) * IN_CAPS + i0 + ii) * K_DIM + 4 * q);
        *(float4*)&xs[bb][ii][4 * q] = v4;
    }
    __syncthreads();

    float acc[2 * BTILE];
#pragma unroll
    for (int j = 0; j < 2 * BTILE; ++j) acc[j] = 0.f;

    float4 wc[8], wn[8];
    {
        const float4* wp = (const float4*)(W + ((size_t)i0 * OD + 2 * t) * K_DIM);
#pragma unroll
        for (int q = 0; q < 8; ++q) wc[q] = wp[q];
    }

    for (int ii = 0; ii < ICH_U; ++ii) {
        const int i = i0 + ii;
        if (ii + 1 < ICH_U) {
            const float4* wp = (const float4*)(W + ((size_t)(i + 1) * OD + 2 * t) * K_DIM);
#pragma unroll
            for (int q = 0; q < 8; ++q) wn[q] = wp[q];   // prefetch next i's W
        }
#pragma unroll
        for (int bb = 0; bb < BTILE; ++bb) {
            const float4 xa = *(const float4*)&xs[bb][ii][0];
            const float4 xb = *(const float4*)&xs[bb][ii][4];
            const float4 xc = *(const float4*)&xs[bb][ii][8];
            const float4 xd = *(const float4*)&xs[bb][ii][12];
            float u0 = dot4(wc[0], xa) + dot4(wc[1], xb) + dot4(wc[2], xc) + dot4(wc[3], xd);
            float u1 = dot4(wc[4], xa) + dot4(wc[5], xb) + dot4(wc[6], xc) + dot4(wc[7], xd);
            acc[2 * bb]     += u0;
            acc[2 * bb + 1] += u1;
            ((float2*)(u + ((size_t)(bl0 + bb) * IN_CAPS + i) * OD))[t] =
                make_float2(u0, u1);
        }
        if (ii + 1 < ICH_U) {
#pragma unroll
            for (int q = 0; q < 8; ++q) wc[q] = wn[q];
        }
    }

#pragma unroll
    for (int bb = 0; bb < BTILE; ++bb) {
        ((float2*)(part + ((size_t)(bl0 + bb) * NCH_U + ib) * OD))[t] =
            make_float2(acc[2 * bb], acc[2 * bb + 1]);
    }
}

// K3/K5 (fused routing pass): per (b,i): a = sum_d u*v; b_ij update; c = softmax_o;
// accumulate partial s += c*u.  Wave layout: lane l -> o = l>>1, d-half = l&1 (8 d's).
template<bool FIRST>
__global__ __launch_bounds__(256)
void k_route(const float* __restrict__ u,    // [nb][2048][512]
             const float* __restrict__ v,    // [nb][512]
             float* __restrict__ bij,        // [nb][2048][32]
             float* __restrict__ part)       // [nb][NCH][512] (route slices)
{
    const int t  = threadIdx.x;
    const int l  = t & 63;
    const int w  = t >> 6;
    const int ic = blockIdx.x;   // 0..NCH-1
    const int b  = blockIdx.y;   // local b
    const int o  = l >> 1;
    const int dh = l & 1;

    float vr[8];
    {
        const float* vp = v + (size_t)b * OD + o * 16 + dh * 8;
        const float4 va = *(const float4*)vp;
        const float4 vb = *(const float4*)(vp + 4);
        vr[0] = va.x; vr[1] = va.y; vr[2] = va.z; vr[3] = va.w;
        vr[4] = vb.x; vr[5] = vb.y; vr[6] = vb.z; vr[7] = vb.w;
    }
    float acc[8];
#pragma unroll
    for (int j = 0; j < 8; ++j) acc[j] = 0.f;

    const int ibase = ic * ICH + w * (ICH / 4);
    for (int ii = 0; ii < ICH / 4; ++ii) {
        const int i = ibase + ii;
        const float* up = u + ((size_t)b * IN_CAPS + i) * OD + l * 8;
        const float4 u0 = *(const float4*)up;
        const float4 u1 = *(const float4*)(up + 4);
        float uu[8] = {u0.x, u0.y, u0.z, u0.w, u1.x, u1.y, u1.z, u1.w};

        float ah = 0.f;
#pragma unroll
        for (int j = 0; j < 8; ++j) ah = fmaf(uu[j], vr[j], ah);
        float a = ah + __shfl_xor(ah, 1);

        float* bp = bij + ((size_t)b * IN_CAPS + i) * 32;
        if (FIRST) {
            if (dh == 0) bp[o] = a;
        } else {
            a += bp[o];
        }
        // softmax over o (each o duplicated on 2 lanes)
        float m = a;
#pragma unroll
        for (int s = 1; s < 64; s <<= 1) m = fmaxf(m, __shfl_xor(m, s));
        const float e = __expf(a - m);
        float ssum = e;
#pragma unroll
        for (int s = 1; s < 64; s <<= 1) ssum += __shfl_xor(ssum, s);
        const float c = e * (2.f / ssum);   // wave-sum counts each o twice
#pragma unroll
        for (int j = 0; j < 8; ++j) acc[j] = fmaf(c, uu[j], acc[j]);
    }

    __shared__ float red[4][OD];
#pragma unroll
    for (int j = 0; j < 8; ++j) red[w][l * 8 + j] = acc[j];
    __syncthreads();
    const float s0 = red[0][t] + red[1][t] + red[2][t] + red[3][t];
    const float s1 = red[0][t + 256] + red[1][t + 256] + red[2][t + 256] + red[3][t + 256];
    float* pp = part + ((size_t)b * NCH + ic) * OD;
    pp[t]       = s0;
    pp[t + 256] = s1;
}

// Reduce partials over NC chunks, apply scale, squash, write v (or d_out).
template<int NC>
__global__ __launch_bounds__(256)
void k_reduce(const float* __restrict__ part, float* __restrict__ vout,
              float scale, int nb)
{
    const int idx = blockIdx.x * 256 + threadIdx.x;
    if (idx >= nb * OD) return;
    const int b  = idx >> 9;
    const int od = idx & (OD - 1);
    const float* p = part + (size_t)b * NC * OD + od;
    float s = 0.f;
#pragma unroll 8
    for (int ch = 0; ch < NC; ++ch) s += p[(size_t)ch * OD];
    s *= scale;
    const float sq = s * s;
    vout[idx] = sq * s / ((1.f + sq) * sqrtf(sq + 1e-8f));
}

extern "C" void kernel_launch(void* const* d_in, const int* in_sizes, int n_in,
                              void* d_out, int out_size, void* d_ws, size_t ws_size,
                              hipStream_t stream)
{
    const float* x = (const float*)d_in[0];   // [64][2048][16]
    const float* W = (const float*)d_in[1];   // [2048][32][16][16]
    float* out = (float*)d_out;               // [64][32][16][1]

    const size_t U_B    = (size_t)IN_CAPS * OD * 4;    // 4 MiB / b
    const size_t BIJ_B  = (size_t)IN_CAPS * 32 * 4;    // 256 KiB / b
    const size_t PART_B = (size_t)NCH_U * OD * 4;      // 1 MiB / b
    const size_t V_B    = (size_t)OD * 4;              // 2 KiB / b
    const size_t PER_B  = U_B + BIJ_B + PART_B + 2 * V_B;

    int nb = 64;
    while (nb > 1 && (size_t)nb * PER_B > ws_size) nb >>= 1;
    // nb=16: per-chunk L3 set = u 67 + W 67 + part 17 MB = 151 MB << 268 MB L3.
    // R7 lesson: nb=32's 284 MB inflow overflowed L3 -> routes fell off the
    // L3 cliff (rest 37us -> 159us). Keep u L3-resident for both route reads.
    if (nb > 16) nb = 16;

    char* wsc = (char*)d_ws;
    for (int b0 = 0; b0 < 64; b0 += nb) {
        float* u    = (float*)wsc;
        float* bij  = (float*)(wsc + (size_t)nb * U_B);
        float* part = (float*)(wsc + (size_t)nb * (U_B + BIJ_B));
        float* v0   = (float*)(wsc + (size_t)nb * (U_B + BIJ_B + PART_B));
        float* v1   = v0 + (size_t)nb * OD;

        const float* xb = x + (size_t)b0 * IN_CAPS * K_DIM;

        const int btile = (nb >= 8) ? 8 : ((nb >= 4) ? 4 : ((nb >= 2) ? 2 : 1));
        dim3 g1(NCH_U, nb / btile);
        switch (btile) {
            case 8: k_uhat<8><<<g1, 256, 0, stream>>>(xb, W, u, part); break;
            case 4: k_uhat<4><<<g1, 256, 0, stream>>>(xb, W, u, part); break;
            case 2: k_uhat<2><<<g1, 256, 0, stream>>>(xb, W, u, part); break;
            default: k_uhat<1><<<g1, 256, 0, stream>>>(xb, W, u, part); break;
        }
        const int rblocks = (nb * OD + 255) / 256;
        k_reduce<NCH_U><<<rblocks, 256, 0, stream>>>(part, v0, 1.f / 32.f, nb);
        k_route<true ><<<dim3(NCH, nb), 256, 0, stream>>>(u, v0, bij, part);
        k_reduce<NCH><<<rblocks, 256, 0, stream>>>(part, v1, 1.f, nb);
        k_route<false><<<dim3(NCH, nb), 256, 0, stream>>>(u, v1, bij, part);
        k_reduce<NCH><<<rblocks, 256, 0, stream>>>(part, out + (size_t)b0 * OD, 1.f, nb);
    }
}

// Round 9
// 245.019 us; speedup vs baseline: 1.5938x; 1.5938x over previous
//
#include <hip/hip_runtime.h>

#define IN_CAPS 2048
#define OD      512                 // out_caps(32) * out_dim(16)
#define ICH_P   16                  // i's per pass block
#define NIC     (IN_CAPS / ICH_P)   // 128 i-chunks (= partial slices)
#define NBC     8                   // b-chunks (8 b each)

__device__ __forceinline__ float dot4(const float4& a, const float4& b) {
    return fmaf(a.x, b.x, fmaf(a.y, b.y, fmaf(a.z, b.z, a.w * b.w)));
}

// Unified recompute pass. MODE 0: s0 = sum_i u / 32 (uniform c).
// MODE 1: a0 = u.v0; bij = a0; c = softmax(a0); s1 partials.
// MODE 2: a1 = u.v1 + bij; c = softmax; s2 partials.
// u_hat is NEVER materialized (R2-R8 lesson: the 256MB u round-trip plus
// W-refetch-per-chunk dominates everything; recompute is 16 MAC/elem).
// Layout: thread t owns od pair (2t, 2t+1); W = 32 VGPR held across 8 b's.
// Softmax: a-partial -> shfl_xor(1,2,4) over the 8-thread o-group ->
// a_buf[8][32] -> thread (b=t>>5, o=t&31) does bij + half-wave-shfl softmax
// -> c_buf broadcast. 2 barriers per i.
// Grid 1024 blocks = 4/CU; XCD swizzle: the 8 b-chunk blocks of an i-chunk
// land on one XCD so each W window is fetched into one L2.
template<int MODE>
__global__ __launch_bounds__(256, 4)
void k_pass(const float* __restrict__ x,     // [64][2048][16]
            const float* __restrict__ W,     // [2048][512][16]
            const float* __restrict__ v,     // [64][512] (MODE 1,2)
            float* __restrict__ bij,         // [64][2048][32]
            float* __restrict__ part)        // [64][NIC][512]
{
    const int t  = threadIdx.x;
    const int s  = blockIdx.x;                    // 0..1023
    const int ic = (s & 7) + 8 * (s >> 6);        // i-chunk (16 per XCD)
    const int bc = (s >> 3) & 7;                  // b-chunk
    const int i0 = ic * ICH_P;
    const int b0 = bc * 8;

    __shared__ float a_buf[8][32];
    __shared__ float c_buf[8][32];

    float vr0[8], vr1[8];
    if (MODE != 0) {
#pragma unroll
        for (int bb = 0; bb < 8; ++bb) {
            const float2 vv = *(const float2*)(v + (size_t)(b0 + bb) * OD + 2 * t);
            vr0[bb] = vv.x; vr1[bb] = vv.y;
        }
    }

    float acc0[8], acc1[8];
#pragma unroll
    for (int bb = 0; bb < 8; ++bb) { acc0[bb] = 0.f; acc1[bb] = 0.f; }

    for (int ii = 0; ii < ICH_P; ++ii) {
        const int i = i0 + ii;
        const float4* wp = (const float4*)(W + ((size_t)i * OD + 2 * t) * 16);
        const float4 w0a = wp[0], w0b = wp[1], w0c = wp[2], w0d = wp[3];
        const float4 w1a = wp[4], w1b = wp[5], w1c = wp[6], w1d = wp[7];

        float u0[8], u1[8];
#pragma unroll
        for (int bb = 0; bb < 8; ++bb) {
            const float4* xp = (const float4*)(x + ((size_t)(b0 + bb) * IN_CAPS + i) * 16);
            const float4 xa = xp[0], xb = xp[1], xc = xp[2], xd = xp[3];
            u0[bb] = dot4(w0a, xa) + dot4(w0b, xb) + dot4(w0c, xc) + dot4(w0d, xd);
            u1[bb] = dot4(w1a, xa) + dot4(w1b, xb) + dot4(w1c, xc) + dot4(w1d, xd);
        }

        if (MODE == 0) {
#pragma unroll
            for (int bb = 0; bb < 8; ++bb) { acc0[bb] += u0[bb]; acc1[bb] += u1[bb]; }
        } else {
            // agreement partials -> per-o sums (8-thread groups, in-wave)
#pragma unroll
            for (int bb = 0; bb < 8; ++bb) {
                float ap = fmaf(u0[bb], vr0[bb], u1[bb] * vr1[bb]);
                ap += __shfl_xor(ap, 1);
                ap += __shfl_xor(ap, 2);
                ap += __shfl_xor(ap, 4);
                if ((t & 7) == 0) a_buf[bb][t >> 3] = ap;
            }
            __syncthreads();
            // softmax finish: thread (b = t>>5, o = t&31), half-wave shfl
            {
                const int b = t >> 5;
                const int o = t & 31;
                float a = a_buf[b][o];
                float* bp = bij + ((size_t)(b0 + b) * IN_CAPS + i) * 32 + o;
                if (MODE == 1) *bp = a;
                else           a += *bp;
                float m = a;
#pragma unroll
                for (int d = 1; d < 32; d <<= 1) m = fmaxf(m, __shfl_xor(m, d));
                const float e = __expf(a - m);
                float sum = e;
#pragma unroll
                for (int d = 1; d < 32; d <<= 1) sum += __shfl_xor(sum, d);
                c_buf[b][o] = e / sum;
            }
            __syncthreads();
#pragma unroll
            for (int bb = 0; bb < 8; ++bb) {
                const float c = c_buf[bb][t >> 3];
                acc0[bb] = fmaf(c, u0[bb], acc0[bb]);
                acc1[bb] = fmaf(c, u1[bb], acc1[bb]);
            }
        }
    }

#pragma unroll
    for (int bb = 0; bb < 8; ++bb) {
        ((float2*)(part + ((size_t)(b0 + bb) * NIC + ic) * OD))[t] =
            make_float2(acc0[bb], acc1[bb]);
    }
}

// Reduce partials over NC slices, apply scale, squash, write v (or d_out).
template<int NC>
__global__ __launch_bounds__(256)
void k_reduce(const float* __restrict__ part, float* __restrict__ vout,
              float scale, int nb)
{
    const int idx = blockIdx.x * 256 + threadIdx.x;
    if (idx >= nb * OD) return;
    const int b  = idx >> 9;
    const int od = idx & (OD - 1);
    const float* p = part + (size_t)b * NC * OD + od;
    float s = 0.f;
#pragma unroll 8
    for (int ch = 0; ch < NC; ++ch) s += p[(size_t)ch * OD];
    s *= scale;
    const float sq = s * s;
    vout[idx] = sq * s / ((1.f + sq) * sqrtf(sq + 1e-8f));
}

extern "C" void kernel_launch(void* const* d_in, const int* in_sizes, int n_in,
                              void* d_out, int out_size, void* d_ws, size_t ws_size,
                              hipStream_t stream)
{
    const float* x = (const float*)d_in[0];   // [64][2048][16]
    const float* W = (const float*)d_in[1];   // [2048][32][16][16]
    float* out = (float*)d_out;               // [64][32][16][1]

    // workspace: bij 16 MB | part 16 MB | v0 128 KB | v1 128 KB  (~32.3 MB)
    char* wsc = (char*)d_ws;
    float* bij  = (float*)wsc;
    float* part = (float*)(wsc + (size_t)64 * IN_CAPS * 32 * 4);
    float* v0   = (float*)(wsc + (size_t)64 * IN_CAPS * 32 * 4
                               + (size_t)64 * NIC * OD * 4);
    float* v1   = v0 + (size_t)64 * OD;

    const int rblocks = 64 * OD / 256;   // 128

    k_pass<0><<<1024, 256, 0, stream>>>(x, W, v0 /*unused*/, bij, part);
    k_reduce<NIC><<<rblocks, 256, 0, stream>>>(part, v0, 1.f / 32.f, 64);
    k_pass<1><<<1024, 256, 0, stream>>>(x, W, v0, bij, part);
    k_reduce<NIC><<<rblocks, 256, 0, stream>>>(part, v1, 1.f, 64);
    k_pass<2><<<1024, 256, 0, stream>>>(x, W, v1, bij, part);
    k_reduce<NIC><<<rblocks, 256, 0, stream>>>(part, out, 1.f, 64);
}